// Round 5
// baseline (185.763 us; speedup 1.0000x reference)
//
#include <hip/hip_runtime.h>

#define N_NODES 100000
#define N_EDGES 800000
#define D 64
#define SCAN_B 1024
#define NB ((N_NODES + SCAN_B - 1) / SCAN_B)   // 98

__device__ __forceinline__ int wave_incl_scan(int v) {
#pragma unroll
    for (int off = 1; off < 64; off <<= 1) {
        int n = __shfl_up(v, off, 64);
        if ((threadIdx.x & 63) >= off) v += n;
    }
    return v;
}

// cnt[col[e]] += 1 (int) for each real edge
__global__ void k_count(const int* __restrict__ col, int* __restrict__ cnt) {
    int e = blockIdx.x * 256 + threadIdx.x;
    if (e < N_EDGES) atomicAdd(&cnt[col[e]], 1);
}

// per-1024-block exclusive scan of cnt -> start (partial), block totals -> bsum
__global__ void k_scan1(const int* __restrict__ cnt, int* __restrict__ start,
                        int* __restrict__ bsum) {
    __shared__ int wsum[16];
    int tid = threadIdx.x;
    int gid = blockIdx.x * SCAN_B + tid;
    int v = (gid < N_NODES) ? cnt[gid] : 0;
    int incl = wave_incl_scan(v);
    int wid = tid >> 6, lane = tid & 63;
    if (lane == 63) wsum[wid] = incl;
    __syncthreads();
    if (wid == 0) {
        int wv = (lane < 16) ? wsum[lane] : 0;
        int wincl = wave_incl_scan(wv);
        if (lane < 16) wsum[lane] = wincl - wv;  // exclusive wave offsets
    }
    __syncthreads();
    int excl = incl - v + wsum[wid];
    if (gid < N_NODES) start[gid] = excl;
    if (tid == SCAN_B - 1) bsum[blockIdx.x] = excl + v;
}

// exclusive scan of the 98 block sums (single block, 128 threads)
__global__ void k_scan2(int* __restrict__ bsum) {
    __shared__ int wsum[2];
    int tid = threadIdx.x;
    int v = (tid < NB) ? bsum[tid] : 0;
    int incl = wave_incl_scan(v);
    int wid = tid >> 6, lane = tid & 63;
    if (lane == 63) wsum[wid] = incl;
    __syncthreads();
    int off = (wid == 1) ? wsum[0] : 0;
    if (tid < NB) bsum[tid] = incl - v + off;
}

// add block offsets; copy to cursor; dinv = rsqrt(cnt+1); start[N]=E
__global__ void k_scan3(int* __restrict__ start, int* __restrict__ cursor,
                        const int* __restrict__ bsum, const int* __restrict__ cnt,
                        float* __restrict__ dinv) {
    int gid = blockIdx.x * SCAN_B + threadIdx.x;
    if (gid < N_NODES) {
        int s = start[gid] + bsum[gid >> 10];
        start[gid] = s;
        cursor[gid] = s;
        dinv[gid] = rsqrtf((float)(cnt[gid] + 1));   // +1 = self-loop
    }
    if (gid == 0) start[N_NODES] = N_EDGES;
}

// bucket edges by target: srow[cursor[col[e]]++] = row[e]
__global__ void k_bucket(const int* __restrict__ row, const int* __restrict__ col,
                         int* __restrict__ cursor, int* __restrict__ srow) {
    int e = blockIdx.x * 256 + threadIdx.x;
    if (e < N_EDGES) {
        int p = atomicAdd(&cursor[col[e]], 1);
        srow[p] = row[e];
    }
}

// xws = dinv * (x @ W). 64 rows/block, 256 threads = 16x16, 4x4 register tile.
// All k-loop LDS traffic is ds_read_b128: 2 b128 per 16 FMA.
#define XW_ROWS 64
#define XSTRIDE (D + 4)   // pad keeps 16B alignment (68 % 4 == 0), breaks bank stride
__global__ __launch_bounds__(256) void k_xw(const float4* __restrict__ x4,
                                            const float4* __restrict__ W4,
                                            const float* __restrict__ dinv,
                                            float4* __restrict__ xws4) {
    __shared__ float Ws[D * D];              // 16 KB
    __shared__ float xs[XW_ROWS][XSTRIDE];   // 17 KB

    int tid = threadIdx.x;
    int base = blockIdx.x * XW_ROWS;

    for (int i = tid; i < D * D / 4; i += 256)
        ((float4*)Ws)[i] = W4[i];
    for (int i = tid; i < XW_ROWS * 16; i += 256) {
        int r = i >> 4, k4 = i & 15;
        int gr = base + r;
        float4 v = (gr < N_NODES) ? x4[(size_t)gr * 16 + k4] : float4{0, 0, 0, 0};
        *(float4*)&xs[r][k4 * 4] = v;
    }
    __syncthreads();

    int tx = tid & 15, ty = tid >> 4;
    int r0 = ty * 4, c0 = tx * 4;

    float4 acc[4] = {{0,0,0,0},{0,0,0,0},{0,0,0,0},{0,0,0,0}};
#pragma unroll
    for (int kq = 0; kq < 16; ++kq) {
        float xr[4][4];
#pragma unroll
        for (int i = 0; i < 4; ++i)
            *(float4*)&xr[i][0] = *(const float4*)&xs[r0 + i][kq * 4];  // broadcast among 16 lanes
#pragma unroll
        for (int q = 0; q < 4; ++q) {
            float4 wv = *(const float4*)&Ws[(kq * 4 + q) * D + c0];     // 2-way aliasing: free
#pragma unroll
            for (int i = 0; i < 4; ++i) {
                acc[i].x = fmaf(xr[i][q], wv.x, acc[i].x);
                acc[i].y = fmaf(xr[i][q], wv.y, acc[i].y);
                acc[i].z = fmaf(xr[i][q], wv.z, acc[i].z);
                acc[i].w = fmaf(xr[i][q], wv.w, acc[i].w);
            }
        }
    }

#pragma unroll
    for (int i = 0; i < 4; ++i) {
        int gr = base + r0 + i;
        if (gr < N_NODES) {
            float di = dinv[gr];
            float4 o = {acc[i].x * di, acc[i].y * di, acc[i].z * di, acc[i].w * di};
            xws4[(size_t)gr * 16 + tx] = o;
        }
    }
}

// One wave per node c, 4 edges in flight (eslot = lane>>4), float4 per lane.
// out[c][:] = b + dinv[c] * (xws[c][:] + sum_e xws[srow[e]][:])
__global__ __launch_bounds__(256) void k_gather(const int* __restrict__ start,
                                                const int* __restrict__ srow,
                                                const float* __restrict__ dinv,
                                                const float4* __restrict__ b4,
                                                const float4* __restrict__ xws4,
                                                float4* __restrict__ out4) {
    int gid = blockIdx.x * 256 + threadIdx.x;
    int c = gid >> 6;
    if (c >= N_NODES) return;
    int lane = threadIdx.x & 63;
    int eslot = lane >> 4;     // which of 4 concurrent edges
    int cg = lane & 15;        // column group (4 floats)

    int s = start[c], e = start[c + 1];
    float4 acc = {0, 0, 0, 0};
    if (eslot == 0) acc = xws4[c * 16 + cg];   // self-loop message (dinv[c]*xw[c])

    for (int base = s; base < e; base += 4) {
        int i = base + eslot;
        if (i < e) {
            int r = srow[i];                    // 16-lane broadcast read
            float4 v = xws4[r * 16 + cg];       // 4 independent 256B rows in flight
            acc.x += v.x; acc.y += v.y; acc.z += v.z; acc.w += v.w;
        }
    }
    // reduce the 4 edge slots (lanes l, l^16, l^32, l^48)
    acc.x += __shfl_xor(acc.x, 16, 64);
    acc.y += __shfl_xor(acc.y, 16, 64);
    acc.z += __shfl_xor(acc.z, 16, 64);
    acc.w += __shfl_xor(acc.w, 16, 64);
    acc.x += __shfl_xor(acc.x, 32, 64);
    acc.y += __shfl_xor(acc.y, 32, 64);
    acc.z += __shfl_xor(acc.z, 32, 64);
    acc.w += __shfl_xor(acc.w, 32, 64);

    if (eslot == 0) {
        float di = dinv[c];
        float4 bb = b4[cg];
        float4 o = {bb.x + di * acc.x, bb.y + di * acc.y,
                    bb.z + di * acc.z, bb.w + di * acc.w};
        out4[c * 16 + cg] = o;
    }
}

extern "C" void kernel_launch(void* const* d_in, const int* in_sizes, int n_in,
                              void* d_out, int out_size, void* d_ws, size_t ws_size,
                              hipStream_t stream) {
    const float* x  = (const float*)d_in[0];
    const int*   ei = (const int*)d_in[1];     // [2, E] int32
    const float* W  = (const float*)d_in[2];
    const float* b  = (const float*)d_in[3];

    const int* row = ei;
    const int* col = ei + N_EDGES;

    // workspace layout, every region 256B-aligned (float4 access to xws)
    char* ws = (char*)d_ws;
    size_t off = 0;
    auto alloc = [&](size_t bytes) {
        char* p = ws + off;
        off = (off + bytes + 255) & ~(size_t)255;
        return p;
    };
    int*   cnt    = (int*)  alloc((size_t)N_NODES * 4);
    float* dinv   = (float*)alloc((size_t)N_NODES * 4);
    int*   start  = (int*)  alloc((size_t)(N_NODES + 1) * 4);
    int*   cursor = (int*)  alloc((size_t)N_NODES * 4);
    int*   bsum   = (int*)  alloc((size_t)NB * 4);
    int*   srow   = (int*)  alloc((size_t)N_EDGES * 4);
    float* xws    = (float*)alloc((size_t)N_NODES * D * 4);
    (void)ws_size;

    hipMemsetAsync(cnt, 0, (size_t)N_NODES * 4, stream);
    k_count <<<(N_EDGES + 255) / 256, 256, 0, stream>>>(col, cnt);
    k_scan1 <<<NB, SCAN_B, 0, stream>>>(cnt, start, bsum);
    k_scan2 <<<1, 128, 0, stream>>>(bsum);
    k_scan3 <<<NB, SCAN_B, 0, stream>>>(start, cursor, bsum, cnt, dinv);
    k_xw    <<<(N_NODES + XW_ROWS - 1) / XW_ROWS, 256, 0, stream>>>(
                (const float4*)x, (const float4*)W, dinv, (float4*)xws);
    k_bucket<<<(N_EDGES + 255) / 256, 256, 0, stream>>>(row, col, cursor, srow);

    long long gt = (long long)N_NODES * D;
    k_gather<<<(int)((gt + 255) / 256), 256, 0, stream>>>(
                start, srow, dinv, (const float4*)b, (const float4*)xws, (float4*)d_out);
}

// Round 6
// 185.575 us; speedup vs baseline: 1.0010x; 1.0010x over previous
//
#include <hip/hip_runtime.h>

#define N_NODES 100000
#define N_EDGES 800000
#define D 64
#define SCAN_B 1024
#define NB ((N_NODES + SCAN_B - 1) / SCAN_B)   // 98

__device__ __forceinline__ int wave_incl_scan(int v) {
#pragma unroll
    for (int off = 1; off < 64; off <<= 1) {
        int n = __shfl_up(v, off, 64);
        if ((threadIdx.x & 63) >= off) v += n;
    }
    return v;
}

// cnt[col[e]] += 1 (int) for each real edge
__global__ void k_count(const int* __restrict__ col, int* __restrict__ cnt) {
    int e = blockIdx.x * 256 + threadIdx.x;
    if (e < N_EDGES) atomicAdd(&cnt[col[e]], 1);
}

// per-1024-block exclusive scan of cnt -> start (partial), block totals -> bsum
__global__ void k_scan1(const int* __restrict__ cnt, int* __restrict__ start,
                        int* __restrict__ bsum) {
    __shared__ int wsum[16];
    int tid = threadIdx.x;
    int gid = blockIdx.x * SCAN_B + tid;
    int v = (gid < N_NODES) ? cnt[gid] : 0;
    int incl = wave_incl_scan(v);
    int wid = tid >> 6, lane = tid & 63;
    if (lane == 63) wsum[wid] = incl;
    __syncthreads();
    if (wid == 0) {
        int wv = (lane < 16) ? wsum[lane] : 0;
        int wincl = wave_incl_scan(wv);
        if (lane < 16) wsum[lane] = wincl - wv;  // exclusive wave offsets
    }
    __syncthreads();
    int excl = incl - v + wsum[wid];
    if (gid < N_NODES) start[gid] = excl;
    if (tid == SCAN_B - 1) bsum[blockIdx.x] = excl + v;
}

// exclusive scan of the 98 block sums (single block, 128 threads)
__global__ void k_scan2(int* __restrict__ bsum) {
    __shared__ int wsum[2];
    int tid = threadIdx.x;
    int v = (tid < NB) ? bsum[tid] : 0;
    int incl = wave_incl_scan(v);
    int wid = tid >> 6, lane = tid & 63;
    if (lane == 63) wsum[wid] = incl;
    __syncthreads();
    int off = (wid == 1) ? wsum[0] : 0;
    if (tid < NB) bsum[tid] = incl - v + off;
}

// add block offsets; copy to cursor; dinv = rsqrt(cnt+1); start[N]=E
__global__ void k_scan3(int* __restrict__ start, int* __restrict__ cursor,
                        const int* __restrict__ bsum, const int* __restrict__ cnt,
                        float* __restrict__ dinv) {
    int gid = blockIdx.x * SCAN_B + threadIdx.x;
    if (gid < N_NODES) {
        int s = start[gid] + bsum[gid >> 10];
        start[gid] = s;
        cursor[gid] = s;
        dinv[gid] = rsqrtf((float)(cnt[gid] + 1));   // +1 = self-loop
    }
    if (gid == 0) start[N_NODES] = N_EDGES;
}

// bucket edges by target: srow[cursor[col[e]]++] = row[e]
__global__ void k_bucket(const int* __restrict__ row, const int* __restrict__ col,
                         int* __restrict__ cursor, int* __restrict__ srow) {
    int e = blockIdx.x * 256 + threadIdx.x;
    if (e < N_EDGES) {
        int p = atomicAdd(&cursor[col[e]], 1);
        srow[p] = row[e];
    }
}

// xws = dinv * (x @ W). 64 rows/block, 256 threads = 16x16, 4x4 register tile.
// All k-loop LDS traffic is ds_read_b128: 2 b128 per 16 FMA.
#define XW_ROWS 64
#define XSTRIDE (D + 4)   // pad keeps 16B alignment (68 % 4 == 0), breaks bank stride
__global__ __launch_bounds__(256) void k_xw(const float4* __restrict__ x4,
                                            const float4* __restrict__ W4,
                                            const float* __restrict__ dinv,
                                            float4* __restrict__ xws4) {
    __shared__ float Ws[D * D];              // 16 KB
    __shared__ float xs[XW_ROWS][XSTRIDE];   // 17 KB

    int tid = threadIdx.x;
    int base = blockIdx.x * XW_ROWS;

    for (int i = tid; i < D * D / 4; i += 256)
        ((float4*)Ws)[i] = W4[i];
    for (int i = tid; i < XW_ROWS * 16; i += 256) {
        int r = i >> 4, k4 = i & 15;
        int gr = base + r;
        float4 v = (gr < N_NODES) ? x4[(size_t)gr * 16 + k4] : float4{0, 0, 0, 0};
        *(float4*)&xs[r][k4 * 4] = v;
    }
    __syncthreads();

    int tx = tid & 15, ty = tid >> 4;
    int r0 = ty * 4, c0 = tx * 4;

    float4 acc[4] = {{0,0,0,0},{0,0,0,0},{0,0,0,0},{0,0,0,0}};
#pragma unroll
    for (int kq = 0; kq < 16; ++kq) {
        float xr[4][4];
#pragma unroll
        for (int i = 0; i < 4; ++i)
            *(float4*)&xr[i][0] = *(const float4*)&xs[r0 + i][kq * 4];  // broadcast among 16 lanes
#pragma unroll
        for (int q = 0; q < 4; ++q) {
            float4 wv = *(const float4*)&Ws[(kq * 4 + q) * D + c0];     // 2-way aliasing: free
#pragma unroll
            for (int i = 0; i < 4; ++i) {
                acc[i].x = fmaf(xr[i][q], wv.x, acc[i].x);
                acc[i].y = fmaf(xr[i][q], wv.y, acc[i].y);
                acc[i].z = fmaf(xr[i][q], wv.z, acc[i].z);
                acc[i].w = fmaf(xr[i][q], wv.w, acc[i].w);
            }
        }
    }

#pragma unroll
    for (int i = 0; i < 4; ++i) {
        int gr = base + r0 + i;
        if (gr < N_NODES) {
            float di = dinv[gr];
            float4 o = {acc[i].x * di, acc[i].y * di, acc[i].z * di, acc[i].w * di};
            xws4[(size_t)gr * 16 + tx] = o;
        }
    }
}

// One wave per node c, 4 edges in flight (eslot = lane>>4), float4 per lane.
// out[c][:] = b + dinv[c] * (xws[c][:] + sum_e xws[srow[e]][:])
__global__ __launch_bounds__(256) void k_gather(const int* __restrict__ start,
                                                const int* __restrict__ srow,
                                                const float* __restrict__ dinv,
                                                const float4* __restrict__ b4,
                                                const float4* __restrict__ xws4,
                                                float4* __restrict__ out4) {
    int gid = blockIdx.x * 256 + threadIdx.x;
    int c = gid >> 6;
    if (c >= N_NODES) return;
    int lane = threadIdx.x & 63;
    int eslot = lane >> 4;     // which of 4 concurrent edges
    int cg = lane & 15;        // column group (4 floats)

    int s = start[c], e = start[c + 1];
    float4 acc = {0, 0, 0, 0};
    if (eslot == 0) acc = xws4[c * 16 + cg];   // self-loop message (dinv[c]*xw[c])

    for (int base = s; base < e; base += 4) {
        int i = base + eslot;
        if (i < e) {
            int r = srow[i];                    // 16-lane broadcast read
            float4 v = xws4[r * 16 + cg];       // 4 independent 256B rows in flight
            acc.x += v.x; acc.y += v.y; acc.z += v.z; acc.w += v.w;
        }
    }
    // reduce the 4 edge slots (lanes l, l^16, l^32, l^48)
    acc.x += __shfl_xor(acc.x, 16, 64);
    acc.y += __shfl_xor(acc.y, 16, 64);
    acc.z += __shfl_xor(acc.z, 16, 64);
    acc.w += __shfl_xor(acc.w, 16, 64);
    acc.x += __shfl_xor(acc.x, 32, 64);
    acc.y += __shfl_xor(acc.y, 32, 64);
    acc.z += __shfl_xor(acc.z, 32, 64);
    acc.w += __shfl_xor(acc.w, 32, 64);

    if (eslot == 0) {
        float di = dinv[c];
        float4 bb = b4[cg];
        float4 o = {bb.x + di * acc.x, bb.y + di * acc.y,
                    bb.z + di * acc.z, bb.w + di * acc.w};
        out4[c * 16 + cg] = o;
    }
}

extern "C" void kernel_launch(void* const* d_in, const int* in_sizes, int n_in,
                              void* d_out, int out_size, void* d_ws, size_t ws_size,
                              hipStream_t stream) {
    const float* x  = (const float*)d_in[0];
    const int*   ei = (const int*)d_in[1];     // [2, E] int32
    const float* W  = (const float*)d_in[2];
    const float* b  = (const float*)d_in[3];

    const int* row = ei;
    const int* col = ei + N_EDGES;

    // workspace layout, every region 256B-aligned (float4 access to xws)
    char* ws = (char*)d_ws;
    size_t off = 0;
    auto alloc = [&](size_t bytes) {
        char* p = ws + off;
        off = (off + bytes + 255) & ~(size_t)255;
        return p;
    };
    int*   cnt    = (int*)  alloc((size_t)N_NODES * 4);
    float* dinv   = (float*)alloc((size_t)N_NODES * 4);
    int*   start  = (int*)  alloc((size_t)(N_NODES + 1) * 4);
    int*   cursor = (int*)  alloc((size_t)N_NODES * 4);
    int*   bsum   = (int*)  alloc((size_t)NB * 4);
    int*   srow   = (int*)  alloc((size_t)N_EDGES * 4);
    float* xws    = (float*)alloc((size_t)N_NODES * D * 4);
    (void)ws_size;

    hipMemsetAsync(cnt, 0, (size_t)N_NODES * 4, stream);
    k_count <<<(N_EDGES + 255) / 256, 256, 0, stream>>>(col, cnt);
    k_scan1 <<<NB, SCAN_B, 0, stream>>>(cnt, start, bsum);
    k_scan2 <<<1, 128, 0, stream>>>(bsum);
    k_scan3 <<<NB, SCAN_B, 0, stream>>>(start, cursor, bsum, cnt, dinv);
    k_xw    <<<(N_NODES + XW_ROWS - 1) / XW_ROWS, 256, 0, stream>>>(
                (const float4*)x, (const float4*)W, dinv, (float4*)xws);
    k_bucket<<<(N_EDGES + 255) / 256, 256, 0, stream>>>(row, col, cursor, srow);

    long long gt = (long long)N_NODES * D;
    k_gather<<<(int)((gt + 255) / 256), 256, 0, stream>>>(
                start, srow, dinv, (const float4*)b, (const float4*)xws, (float4*)d_out);
}

// Round 7
// 150.254 us; speedup vs baseline: 1.2363x; 1.2351x over previous
//
#include <hip/hip_runtime.h>

#define N_NODES 100000
#define N_EDGES 800000
#define D 64
#define SCAN_B 1024
#define NB ((N_NODES + SCAN_B - 1) / SCAN_B)   // 98

#define XCD_N 8
#define COLS_PER_XCD ((N_NODES + XCD_N - 1) / XCD_N)       // 12500
#define BKT_CHUNK 2048
#define BKT_CHUNKS ((N_EDGES + BKT_CHUNK - 1) / BKT_CHUNK) // 391

__device__ __forceinline__ int wave_incl_scan(int v) {
#pragma unroll
    for (int off = 1; off < 64; off <<= 1) {
        int n = __shfl_up(v, off, 64);
        if ((threadIdx.x & 63) >= off) v += n;
    }
    return v;
}

// XCD-partitioned degree count: group g = blockIdx&7 only counts cols in its
// 12500-node range, so cnt-line atomics stay in one XCD's L2.
__global__ void k_count(const int* __restrict__ col, int* __restrict__ cnt) {
    int g = blockIdx.x & 7;
    int chunk = blockIdx.x >> 3;
    int lo = g * COLS_PER_XCD, hi = lo + COLS_PER_XCD;
    int e1 = min((chunk + 1) * BKT_CHUNK, N_EDGES);
    for (int e = chunk * BKT_CHUNK + threadIdx.x; e < e1; e += 256) {
        int c = col[e];
        if (c >= lo && c < hi) atomicAdd(&cnt[c], 1);
    }
}

// per-1024-block exclusive scan of cnt -> start (partial), block totals -> bsum
__global__ void k_scan1(const int* __restrict__ cnt, int* __restrict__ start,
                        int* __restrict__ bsum) {
    __shared__ int wsum[16];
    int tid = threadIdx.x;
    int gid = blockIdx.x * SCAN_B + tid;
    int v = (gid < N_NODES) ? cnt[gid] : 0;
    int incl = wave_incl_scan(v);
    int wid = tid >> 6, lane = tid & 63;
    if (lane == 63) wsum[wid] = incl;
    __syncthreads();
    if (wid == 0) {
        int wv = (lane < 16) ? wsum[lane] : 0;
        int wincl = wave_incl_scan(wv);
        if (lane < 16) wsum[lane] = wincl - wv;  // exclusive wave offsets
    }
    __syncthreads();
    int excl = incl - v + wsum[wid];
    if (gid < N_NODES) start[gid] = excl;
    if (tid == SCAN_B - 1) bsum[blockIdx.x] = excl + v;
}

// exclusive scan of the 98 block sums (single block, 128 threads)
__global__ void k_scan2(int* __restrict__ bsum) {
    __shared__ int wsum[2];
    int tid = threadIdx.x;
    int v = (tid < NB) ? bsum[tid] : 0;
    int incl = wave_incl_scan(v);
    int wid = tid >> 6, lane = tid & 63;
    if (lane == 63) wsum[wid] = incl;
    __syncthreads();
    int off = (wid == 1) ? wsum[0] : 0;
    if (tid < NB) bsum[tid] = incl - v + off;
}

// add block offsets; copy to cursor; dinv = rsqrt(cnt+1); start[N]=E
__global__ void k_scan3(int* __restrict__ start, int* __restrict__ cursor,
                        const int* __restrict__ bsum, const int* __restrict__ cnt,
                        float* __restrict__ dinv) {
    int gid = blockIdx.x * SCAN_B + threadIdx.x;
    if (gid < N_NODES) {
        int s = start[gid] + bsum[gid >> 10];
        start[gid] = s;
        cursor[gid] = s;
        dinv[gid] = rsqrtf((float)(cnt[gid] + 1));   // +1 = self-loop
    }
    if (gid == 0) start[N_NODES] = N_EDGES;
}

// XCD-partitioned bucket: group g only places edges whose target is in its
// col-range -> cursor atomics AND the ~400KB srow slice are single-XCD-local
// (write lines stay in that L2, written back once instead of 16x amplified).
__global__ void k_bucket(const int* __restrict__ row, const int* __restrict__ col,
                         int* __restrict__ cursor, int* __restrict__ srow) {
    int g = blockIdx.x & 7;
    int chunk = blockIdx.x >> 3;
    int lo = g * COLS_PER_XCD, hi = lo + COLS_PER_XCD;
    int e1 = min((chunk + 1) * BKT_CHUNK, N_EDGES);
    for (int e = chunk * BKT_CHUNK + threadIdx.x; e < e1; e += 256) {
        int c = col[e];
        if (c >= lo && c < hi) {
            int p = atomicAdd(&cursor[c], 1);
            srow[p] = row[e];
        }
    }
}

static __device__ __forceinline__ float f4c(const float4& v, int q) {
    return q == 0 ? v.x : q == 1 ? v.y : q == 2 ? v.z : v.w;  // static after unroll
}

// xws = dinv * (x @ W). 64 rows/block, 256 threads = 16x16, 4x4 register tile.
// launch_bounds(256,4): cap VGPR at 128 (round-6 version hit 240 -> 8.8% occ).
// unroll 2 keeps the software pipeline shallow so regalloc stays under the cap.
#define XW_ROWS 64
#define XSTRIDE (D + 4)   // 272B row stride: 16B-aligned, rows 4 apart hit 2-way banks (free)
__global__ __launch_bounds__(256, 4) void k_xw(const float4* __restrict__ x4,
                                               const float4* __restrict__ W4,
                                               const float* __restrict__ dinv,
                                               float4* __restrict__ xws4) {
    __shared__ float Ws[D * D];              // 16 KB
    __shared__ float xs[XW_ROWS][XSTRIDE];   // 17 KB

    int tid = threadIdx.x;
    int base = blockIdx.x * XW_ROWS;

    for (int i = tid; i < D * D / 4; i += 256)
        ((float4*)Ws)[i] = W4[i];
    for (int i = tid; i < XW_ROWS * 16; i += 256) {
        int r = i >> 4, k4 = i & 15;
        int gr = base + r;
        float4 v = (gr < N_NODES) ? x4[(size_t)gr * 16 + k4] : float4{0, 0, 0, 0};
        *(float4*)&xs[r][k4 * 4] = v;
    }
    __syncthreads();

    int tx = tid & 15, ty = tid >> 4;
    int r0 = ty * 4, c0 = tx * 4;

    float4 a0{0,0,0,0}, a1{0,0,0,0}, a2{0,0,0,0}, a3{0,0,0,0};
#pragma unroll 2
    for (int kq = 0; kq < 16; ++kq) {
        float4 x0 = *(const float4*)&xs[r0 + 0][kq * 4];
        float4 x1 = *(const float4*)&xs[r0 + 1][kq * 4];
        float4 x2 = *(const float4*)&xs[r0 + 2][kq * 4];
        float4 x3 = *(const float4*)&xs[r0 + 3][kq * 4];
#pragma unroll
        for (int q = 0; q < 4; ++q) {
            float4 wv = *(const float4*)&Ws[(kq * 4 + q) * D + c0];
            float s0 = f4c(x0, q), s1 = f4c(x1, q), s2 = f4c(x2, q), s3 = f4c(x3, q);
            a0.x = fmaf(s0, wv.x, a0.x); a0.y = fmaf(s0, wv.y, a0.y);
            a0.z = fmaf(s0, wv.z, a0.z); a0.w = fmaf(s0, wv.w, a0.w);
            a1.x = fmaf(s1, wv.x, a1.x); a1.y = fmaf(s1, wv.y, a1.y);
            a1.z = fmaf(s1, wv.z, a1.z); a1.w = fmaf(s1, wv.w, a1.w);
            a2.x = fmaf(s2, wv.x, a2.x); a2.y = fmaf(s2, wv.y, a2.y);
            a2.z = fmaf(s2, wv.z, a2.z); a2.w = fmaf(s2, wv.w, a2.w);
            a3.x = fmaf(s3, wv.x, a3.x); a3.y = fmaf(s3, wv.y, a3.y);
            a3.z = fmaf(s3, wv.z, a3.z); a3.w = fmaf(s3, wv.w, a3.w);
        }
    }

    float4 accs[4] = {a0, a1, a2, a3};
#pragma unroll
    for (int i = 0; i < 4; ++i) {
        int gr = base + r0 + i;
        if (gr < N_NODES) {
            float di = dinv[gr];
            float4 o = {accs[i].x * di, accs[i].y * di, accs[i].z * di, accs[i].w * di};
            xws4[(size_t)gr * 16 + tx] = o;
        }
    }
}

// One wave per node c, 4 edges in flight (eslot = lane>>4), float4 per lane.
// Block swizzle matches k_bucket's partition: blocks with blockIdx&7==g handle
// nodes in group g's range, so start/srow/out lines are read from the same
// XCD L2 that k_bucket just wrote.
__global__ __launch_bounds__(256) void k_gather(const int* __restrict__ start,
                                                const int* __restrict__ srow,
                                                const float* __restrict__ dinv,
                                                const float4* __restrict__ b4,
                                                const float4* __restrict__ xws4,
                                                float4* __restrict__ out4) {
    int g = blockIdx.x & 7;                       // 8 groups x 3125 blocks
    int local = blockIdx.x >> 3;                  // 4 nodes per block
    int c = g * COLS_PER_XCD + local * 4 + (int)(threadIdx.x >> 6);
    if (c >= N_NODES) return;
    int lane = threadIdx.x & 63;
    int eslot = lane >> 4;     // which of 4 concurrent edges
    int cg = lane & 15;        // column group (4 floats)

    int s = start[c], e = start[c + 1];
    float4 acc = {0, 0, 0, 0};
    if (eslot == 0) acc = xws4[c * 16 + cg];   // self-loop message (dinv[c]*xw[c])

    for (int base = s; base < e; base += 4) {
        int i = base + eslot;
        if (i < e) {
            int r = srow[i];                    // 16-lane broadcast read
            float4 v = xws4[r * 16 + cg];       // 4 independent 256B rows in flight
            acc.x += v.x; acc.y += v.y; acc.z += v.z; acc.w += v.w;
        }
    }
    // reduce the 4 edge slots (lanes l, l^16, l^32, l^48)
    acc.x += __shfl_xor(acc.x, 16, 64);
    acc.y += __shfl_xor(acc.y, 16, 64);
    acc.z += __shfl_xor(acc.z, 16, 64);
    acc.w += __shfl_xor(acc.w, 16, 64);
    acc.x += __shfl_xor(acc.x, 32, 64);
    acc.y += __shfl_xor(acc.y, 32, 64);
    acc.z += __shfl_xor(acc.z, 32, 64);
    acc.w += __shfl_xor(acc.w, 32, 64);

    if (eslot == 0) {
        float di = dinv[c];
        float4 bb = b4[cg];
        float4 o = {bb.x + di * acc.x, bb.y + di * acc.y,
                    bb.z + di * acc.z, bb.w + di * acc.w};
        out4[c * 16 + cg] = o;
    }
}

extern "C" void kernel_launch(void* const* d_in, const int* in_sizes, int n_in,
                              void* d_out, int out_size, void* d_ws, size_t ws_size,
                              hipStream_t stream) {
    const float* x  = (const float*)d_in[0];
    const int*   ei = (const int*)d_in[1];     // [2, E] int32
    const float* W  = (const float*)d_in[2];
    const float* b  = (const float*)d_in[3];

    const int* row = ei;
    const int* col = ei + N_EDGES;

    // workspace layout, every region 256B-aligned (float4 access to xws)
    char* ws = (char*)d_ws;
    size_t off = 0;
    auto alloc = [&](size_t bytes) {
        char* p = ws + off;
        off = (off + bytes + 255) & ~(size_t)255;
        return p;
    };
    int*   cnt    = (int*)  alloc((size_t)N_NODES * 4);
    float* dinv   = (float*)alloc((size_t)N_NODES * 4);
    int*   start  = (int*)  alloc((size_t)(N_NODES + 1) * 4);
    int*   cursor = (int*)  alloc((size_t)N_NODES * 4);
    int*   bsum   = (int*)  alloc((size_t)NB * 4);
    int*   srow   = (int*)  alloc((size_t)N_EDGES * 4);
    float* xws    = (float*)alloc((size_t)N_NODES * D * 4);
    (void)ws_size;

    hipMemsetAsync(cnt, 0, (size_t)N_NODES * 4, stream);
    k_count <<<BKT_CHUNKS * XCD_N, 256, 0, stream>>>(col, cnt);
    k_scan1 <<<NB, SCAN_B, 0, stream>>>(cnt, start, bsum);
    k_scan2 <<<1, 128, 0, stream>>>(bsum);
    k_scan3 <<<NB, SCAN_B, 0, stream>>>(start, cursor, bsum, cnt, dinv);
    k_xw    <<<(N_NODES + XW_ROWS - 1) / XW_ROWS, 256, 0, stream>>>(
                (const float4*)x, (const float4*)W, dinv, (float4*)xws);
    k_bucket<<<BKT_CHUNKS * XCD_N, 256, 0, stream>>>(row, col, cursor, srow);

    long long gt = (long long)N_NODES * D;
    k_gather<<<(int)((gt + 255) / 256), 256, 0, stream>>>(
                start, srow, dinv, (const float4*)b, (const float4*)xws, (float4*)d_out);
}

// Round 8
// 142.712 us; speedup vs baseline: 1.3017x; 1.0528x over previous
//
#include <hip/hip_runtime.h>

#define N_NODES 100000
#define N_EDGES 800000
#define D 64
#define SCAN_B 1024
#define NB ((N_NODES + SCAN_B - 1) / SCAN_B)   // 98

#define XCD_N 8
#define COLS_PER_XCD ((N_NODES + XCD_N - 1) / XCD_N)       // 12500
#define N_E4 (N_EDGES / 4)                                 // 200000 (E % 4 == 0)
#define BKT_C4 512                                         // int4s per chunk (2048 edges)
#define BKT_CHUNKS ((N_E4 + BKT_C4 - 1) / BKT_C4)          // 391

__device__ __forceinline__ int wave_incl_scan(int v) {
#pragma unroll
    for (int off = 1; off < 64; off <<= 1) {
        int n = __shfl_up(v, off, 64);
        if ((threadIdx.x & 63) >= off) v += n;
    }
    return v;
}

// round-to-nearest-even f32 -> bf16 pair packed in one uint
__device__ __forceinline__ unsigned pack_bf16x2(float a, float b) {
    unsigned ua = __float_as_uint(a);
    ua = (ua + 0x7FFFu + ((ua >> 16) & 1u)) >> 16;
    unsigned ub = __float_as_uint(b);
    ub = (ub + 0x7FFFu + ((ub >> 16) & 1u)) >> 16;
    return ua | (ub << 16);
}

// XCD-partitioned degree count, int4-vectorized col stream
__global__ void k_count(const int4* __restrict__ col4, int* __restrict__ cnt) {
    int g = blockIdx.x & 7;
    int chunk = blockIdx.x >> 3;
    int lo = g * COLS_PER_XCD, hi = lo + COLS_PER_XCD;
    int v1 = min((chunk + 1) * BKT_C4, N_E4);
    for (int v = chunk * BKT_C4 + threadIdx.x; v < v1; v += 256) {
        int4 q = col4[v];
        if (q.x >= lo && q.x < hi) atomicAdd(&cnt[q.x], 1);
        if (q.y >= lo && q.y < hi) atomicAdd(&cnt[q.y], 1);
        if (q.z >= lo && q.z < hi) atomicAdd(&cnt[q.z], 1);
        if (q.w >= lo && q.w < hi) atomicAdd(&cnt[q.w], 1);
    }
}

// per-1024-block exclusive scan of cnt -> start (partial), totals -> bsum; dinv fused
__global__ void k_scan1(const int* __restrict__ cnt, int* __restrict__ start,
                        int* __restrict__ bsum, float* __restrict__ dinv) {
    __shared__ int wsum[16];
    int tid = threadIdx.x;
    int gid = blockIdx.x * SCAN_B + tid;
    int v = (gid < N_NODES) ? cnt[gid] : 0;
    if (gid < N_NODES) dinv[gid] = rsqrtf((float)(v + 1));   // +1 = self-loop
    int incl = wave_incl_scan(v);
    int wid = tid >> 6, lane = tid & 63;
    if (lane == 63) wsum[wid] = incl;
    __syncthreads();
    if (wid == 0) {
        int wv = (lane < 16) ? wsum[lane] : 0;
        int wincl = wave_incl_scan(wv);
        if (lane < 16) wsum[lane] = wincl - wv;
    }
    __syncthreads();
    int excl = incl - v + wsum[wid];
    if (gid < N_NODES) start[gid] = excl;
    if (tid == SCAN_B - 1) bsum[blockIdx.x] = excl + v;
}

// exclusive scan of the 98 block sums
__global__ void k_scan2(int* __restrict__ bsum) {
    __shared__ int wsum[2];
    int tid = threadIdx.x;
    int v = (tid < NB) ? bsum[tid] : 0;
    int incl = wave_incl_scan(v);
    int wid = tid >> 6, lane = tid & 63;
    if (lane == 63) wsum[wid] = incl;
    __syncthreads();
    int off = (wid == 1) ? wsum[0] : 0;
    if (tid < NB) bsum[tid] = incl - v + off;
}

// add block offsets; copy to cursor; start[N]=E
__global__ void k_scan3(int* __restrict__ start, int* __restrict__ cursor,
                        const int* __restrict__ bsum) {
    int gid = blockIdx.x * SCAN_B + threadIdx.x;
    if (gid < N_NODES) {
        int s = start[gid] + bsum[gid >> 10];
        start[gid] = s;
        cursor[gid] = s;
    }
    if (gid == 0) start[N_NODES] = N_EDGES;
}

// XCD-partitioned bucket: cursor atomics + srow slice stay in one XCD's L2
__global__ void k_bucket(const int* __restrict__ row, const int4* __restrict__ col4,
                         int* __restrict__ cursor, int* __restrict__ srow) {
    int g = blockIdx.x & 7;
    int chunk = blockIdx.x >> 3;
    int lo = g * COLS_PER_XCD, hi = lo + COLS_PER_XCD;
    int v1 = min((chunk + 1) * BKT_C4, N_E4);
    for (int v = chunk * BKT_C4 + threadIdx.x; v < v1; v += 256) {
        int4 q = col4[v];
        int e = v * 4;
        if (q.x >= lo && q.x < hi) { int p = atomicAdd(&cursor[q.x], 1); srow[p] = row[e + 0]; }
        if (q.y >= lo && q.y < hi) { int p = atomicAdd(&cursor[q.y], 1); srow[p] = row[e + 1]; }
        if (q.z >= lo && q.z < hi) { int p = atomicAdd(&cursor[q.z], 1); srow[p] = row[e + 2]; }
        if (q.w >= lo && q.w < hi) { int p = atomicAdd(&cursor[q.w], 1); srow[p] = row[e + 3]; }
    }
}

static __device__ __forceinline__ float f4c(const float4& v, int q) {
    return q == 0 ? v.x : q == 1 ? v.y : q == 2 ? v.z : v.w;  // static after unroll
}

// xws = bf16(dinv * (x @ W)). 64 rows/block, 16x16 threads, 4x4 register tile.
#define XW_ROWS 64
#define XSTRIDE (D + 4)
__global__ __launch_bounds__(256, 4) void k_xw(const float4* __restrict__ x4,
                                               const float4* __restrict__ W4,
                                               const float* __restrict__ dinv,
                                               unsigned short* __restrict__ xh) {
    __shared__ float Ws[D * D];              // 16 KB
    __shared__ float xs[XW_ROWS][XSTRIDE];   // 17 KB

    int tid = threadIdx.x;
    int base = blockIdx.x * XW_ROWS;

    for (int i = tid; i < D * D / 4; i += 256)
        ((float4*)Ws)[i] = W4[i];
    for (int i = tid; i < XW_ROWS * 16; i += 256) {
        int r = i >> 4, k4 = i & 15;
        int gr = base + r;
        float4 v = (gr < N_NODES) ? x4[(size_t)gr * 16 + k4] : float4{0, 0, 0, 0};
        *(float4*)&xs[r][k4 * 4] = v;
    }
    __syncthreads();

    int tx = tid & 15, ty = tid >> 4;
    int r0 = ty * 4, c0 = tx * 4;

    float4 a0{0,0,0,0}, a1{0,0,0,0}, a2{0,0,0,0}, a3{0,0,0,0};
#pragma unroll 2
    for (int kq = 0; kq < 16; ++kq) {
        float4 x0 = *(const float4*)&xs[r0 + 0][kq * 4];
        float4 x1 = *(const float4*)&xs[r0 + 1][kq * 4];
        float4 x2 = *(const float4*)&xs[r0 + 2][kq * 4];
        float4 x3 = *(const float4*)&xs[r0 + 3][kq * 4];
#pragma unroll
        for (int q = 0; q < 4; ++q) {
            float4 wv = *(const float4*)&Ws[(kq * 4 + q) * D + c0];
            float s0 = f4c(x0, q), s1 = f4c(x1, q), s2 = f4c(x2, q), s3 = f4c(x3, q);
            a0.x = fmaf(s0, wv.x, a0.x); a0.y = fmaf(s0, wv.y, a0.y);
            a0.z = fmaf(s0, wv.z, a0.z); a0.w = fmaf(s0, wv.w, a0.w);
            a1.x = fmaf(s1, wv.x, a1.x); a1.y = fmaf(s1, wv.y, a1.y);
            a1.z = fmaf(s1, wv.z, a1.z); a1.w = fmaf(s1, wv.w, a1.w);
            a2.x = fmaf(s2, wv.x, a2.x); a2.y = fmaf(s2, wv.y, a2.y);
            a2.z = fmaf(s2, wv.z, a2.z); a2.w = fmaf(s2, wv.w, a2.w);
            a3.x = fmaf(s3, wv.x, a3.x); a3.y = fmaf(s3, wv.y, a3.y);
            a3.z = fmaf(s3, wv.z, a3.z); a3.w = fmaf(s3, wv.w, a3.w);
        }
    }

    float4 accs[4] = {a0, a1, a2, a3};
#pragma unroll
    for (int i = 0; i < 4; ++i) {
        int gr = base + r0 + i;
        if (gr < N_NODES) {
            float di = dinv[gr];
            unsigned p01 = pack_bf16x2(accs[i].x * di, accs[i].y * di);
            unsigned p23 = pack_bf16x2(accs[i].z * di, accs[i].w * di);
            *(uint2*)&xh[(size_t)gr * D + c0] = uint2{p01, p23};
        }
    }
}

// One wave per node c. bf16 rows are 128B: 8 edges in flight (eslot=lane>>3),
// each lane loads uint4 = 8 bf16, accumulates fp32, 3 shfl_xor rounds reduce.
__global__ __launch_bounds__(256) void k_gather(const int* __restrict__ start,
                                                const int* __restrict__ srow,
                                                const float* __restrict__ dinv,
                                                const float4* __restrict__ b4,
                                                const uint4* __restrict__ xh4,
                                                float4* __restrict__ out4) {
    int g = blockIdx.x & 7;                       // matches k_bucket's XCD partition
    int local = blockIdx.x >> 3;
    int c = g * COLS_PER_XCD + local * 4 + (int)(threadIdx.x >> 6);
    if (c >= N_NODES) return;
    int lane = threadIdx.x & 63;
    int eslot = lane >> 3;     // which of 8 concurrent edges
    int cg = lane & 7;         // column group (8 bf16 = 16B)

    int s = start[c], e = start[c + 1];
    float a[8] = {0, 0, 0, 0, 0, 0, 0, 0};
    if (eslot == 0) {          // self-loop message (dinv[c]*xw[c])
        uint4 q = xh4[(size_t)c * 8 + cg];
        a[0] = __uint_as_float(q.x << 16); a[1] = __uint_as_float(q.x & 0xFFFF0000u);
        a[2] = __uint_as_float(q.y << 16); a[3] = __uint_as_float(q.y & 0xFFFF0000u);
        a[4] = __uint_as_float(q.z << 16); a[5] = __uint_as_float(q.z & 0xFFFF0000u);
        a[6] = __uint_as_float(q.w << 16); a[7] = __uint_as_float(q.w & 0xFFFF0000u);
    }

    for (int base = s; base < e; base += 8) {
        int i = base + eslot;
        if (i < e) {
            int r = srow[i];                       // 8-lane broadcast read
            uint4 q = xh4[(size_t)r * 8 + cg];     // 8 independent 128B rows in flight
            a[0] += __uint_as_float(q.x << 16); a[1] += __uint_as_float(q.x & 0xFFFF0000u);
            a[2] += __uint_as_float(q.y << 16); a[3] += __uint_as_float(q.y & 0xFFFF0000u);
            a[4] += __uint_as_float(q.z << 16); a[5] += __uint_as_float(q.z & 0xFFFF0000u);
            a[6] += __uint_as_float(q.w << 16); a[7] += __uint_as_float(q.w & 0xFFFF0000u);
        }
    }

    // reduce the 8 edge slots (lane bits 3,4,5)
#pragma unroll
    for (int m = 8; m <= 32; m <<= 1) {
#pragma unroll
        for (int j = 0; j < 8; ++j) a[j] += __shfl_xor(a[j], m, 64);
    }

    if (eslot == 0) {
        float di = dinv[c];
        float4 b0 = b4[cg * 2], b1 = b4[cg * 2 + 1];
        out4[(size_t)c * 16 + cg * 2] =
            float4{b0.x + di * a[0], b0.y + di * a[1], b0.z + di * a[2], b0.w + di * a[3]};
        out4[(size_t)c * 16 + cg * 2 + 1] =
            float4{b1.x + di * a[4], b1.y + di * a[5], b1.z + di * a[6], b1.w + di * a[7]};
    }
}

extern "C" void kernel_launch(void* const* d_in, const int* in_sizes, int n_in,
                              void* d_out, int out_size, void* d_ws, size_t ws_size,
                              hipStream_t stream) {
    const float* x  = (const float*)d_in[0];
    const int*   ei = (const int*)d_in[1];     // [2, E] int32
    const float* W  = (const float*)d_in[2];
    const float* b  = (const float*)d_in[3];

    const int* row = ei;
    const int* col = ei + N_EDGES;

    // workspace layout, every region 256B-aligned
    char* ws = (char*)d_ws;
    size_t off = 0;
    auto alloc = [&](size_t bytes) {
        char* p = ws + off;
        off = (off + bytes + 255) & ~(size_t)255;
        return p;
    };
    int*   cnt    = (int*)  alloc((size_t)N_NODES * 4);
    float* dinv   = (float*)alloc((size_t)N_NODES * 4);
    int*   start  = (int*)  alloc((size_t)(N_NODES + 1) * 4);
    int*   cursor = (int*)  alloc((size_t)N_NODES * 4);
    int*   bsum   = (int*)  alloc((size_t)NB * 4);
    int*   srow   = (int*)  alloc((size_t)N_EDGES * 4);
    unsigned short* xh = (unsigned short*)alloc((size_t)N_NODES * D * 2);  // bf16
    (void)ws_size;

    hipMemsetAsync(cnt, 0, (size_t)N_NODES * 4, stream);
    k_count <<<BKT_CHUNKS * XCD_N, 256, 0, stream>>>((const int4*)col, cnt);
    k_scan1 <<<NB, SCAN_B, 0, stream>>>(cnt, start, bsum, dinv);
    k_scan2 <<<1, 128, 0, stream>>>(bsum);
    k_scan3 <<<NB, SCAN_B, 0, stream>>>(start, cursor, bsum);
    k_xw    <<<(N_NODES + XW_ROWS - 1) / XW_ROWS, 256, 0, stream>>>(
                (const float4*)x, (const float4*)W, dinv, xh);
    k_bucket<<<BKT_CHUNKS * XCD_N, 256, 0, stream>>>(row, (const int4*)col, cursor, srow);

    long long gt = (long long)N_NODES * D;
    k_gather<<<(int)((gt + 255) / 256), 256, 0, stream>>>(
                start, srow, dinv, (const float4*)b, (const uint4*)xh, (float4*)d_out);
}